// Round 8
// baseline (89.637 us; speedup 1.0000x reference)
//
#include <hip/hip_runtime.h>
#include <math.h>
#include <limits.h>

#define NCHUNK 16
#define PLACEHOLDER (-1)

typedef float f32x4 __attribute__((ext_vector_type(4)));
typedef unsigned long long u64;

// exp(x - 16), computed as exp2(x*log2e - 16*log2e). No running max needed:
// logits are O(1), so terms are ~1e-7 and the 128K-term sum ~1e-2 -- all
// comfortably inside f32 range. Softmax p = fexp(l) / sum(fexp(l)).
__device__ __forceinline__ float fexp(float x) {
  return exp2f(fmaf(x, 1.44269504088896340736f, -23.0831206542234143f));
}

// (max, index) combine with first-occurrence tie-break (lower index wins).
__device__ __forceinline__ void comb_mx(float& m, int& i, float m2, int i2) {
  if (m2 > m || (m2 == m && i2 < i)) { m = m2; i = i2; }
}

// Accept decision for one row: linear Z sum in chunk order (deterministic,
// identical everywhere it's evaluated), fexp, divide, compare.
__device__ __forceinline__ int accept_row(
    const float* __restrict__ logits, const float* __restrict__ draft,
    const int* __restrict__ dids, const float* __restrict__ uniform,
    const float* __restrict__ ps, int row, int V, float& Zout) {
  float Z = 0.f;
#pragma unroll
  for (int c = 0; c < NCHUNK; ++c) Z += ps[row * NCHUNK + c];
  Zout = Z;
  const int tok = dids[row];
  const float t_at = fexp(logits[(size_t)row * V + tok]) / Z;
  const float d_at = draft[(size_t)row * V + tok];
  const float u = uniform[row];
  return (d_at > 0.f && (t_at / d_at) >= u) ? 1 : 0;
}

// Pass 1: greedy rows -> per-chunk {max, argmax}; random rows -> per-chunk
// sum of exp(l-16). Chunk-0 blocks also reset the slot/done sync cells for
// pass 2 (no separate memset launch; kernel boundary publishes the stores).
__global__ __launch_bounds__(256) void k_stats(
    const float* __restrict__ logits, const int* __restrict__ topk,
    float* __restrict__ pm, float* __restrict__ ps, int* __restrict__ pidx,
    u64* __restrict__ slot, int* __restrict__ done,
    int S, int V, int chunk_elems) {
  const int row = blockIdx.y;
  const int chunk = blockIdx.x;
  const int tid = threadIdx.x;
  const int b = row / S;
  const int begin = chunk * chunk_elems;
  const int end = min(begin + chunk_elems, V);
  const int n = max(end - begin, 0);
  const int c4 = n >> 2;
  const float* lrow = logits + (size_t)row * V;
  const f32x4* l4 = (const f32x4*)(lrow + begin);
  const int item = row * NCHUNK + chunk;

  if (chunk == 0 && tid == 0) {
    slot[row] = 0ull;
    if (row == b * S) done[b] = 0;
  }

  __shared__ float shf[4];
  __shared__ int shi[4];
  const int lane = tid & 63;
  const int wv = tid >> 6;

  if (topk[b] == 1) {
    // ---- greedy: max + argmax only ----
    float m = -INFINITY; int mi = INT_MAX;
    for (int i = tid; i < c4; i += 256) {
      f32x4 v = l4[i];
      const int gi = begin + (i << 2);
#pragma unroll
      for (int k = 0; k < 4; ++k)
        if (v[k] > m) { m = v[k]; mi = gi + k; }   // strict >: first idx kept
    }
    for (int j = begin + (c4 << 2) + tid; j < end; j += 256) {
      float x = lrow[j];
      if (x > m) { m = x; mi = j; }
    }
    for (int off = 32; off; off >>= 1) {
      float m2 = __shfl_xor(m, off);
      int   i2 = __shfl_xor(mi, off);
      comb_mx(m, mi, m2, i2);
    }
    if (lane == 0) { shf[wv] = m; shi[wv] = mi; }
    __syncthreads();
    if (tid == 0) {
#pragma unroll
      for (int w = 1; w < 4; ++w) comb_mx(m, mi, shf[w], shi[w]);
      pm[item] = m; pidx[item] = mi;
    }
  } else {
    // ---- random: branchless sum of exp(l - 16) ----
    float ssum = 0.f;
    for (int i = tid; i < c4; i += 256) {
      f32x4 v = l4[i];
      ssum += fexp(v[0]); ssum += fexp(v[1]);
      ssum += fexp(v[2]); ssum += fexp(v[3]);
    }
    for (int j = begin + (c4 << 2) + tid; j < end; j += 256)
      ssum += fexp(lrow[j]);
    for (int off = 32; off; off >>= 1)
      ssum += __shfl_xor(ssum, off);
    if (lane == 0) shf[wv] = ssum;
    __syncthreads();
    if (tid == 0)
      ps[item] = shf[0] + shf[1] + shf[2] + shf[3];
  }
}

// Pass 2 + finalize. Roles per block (row, chunk):
//  greedy b:            (s==0, chunk==0) finalizes from pm/pidx; rest exit.
//  non-greedy, no rej:  (s==0, chunk==0) finalizes (all drafts + bonus).
//  non-greedy, rej @f:  the 16 chunk-blocks of row f scan score, atomicMax a
//                       packed (score_bits<<32 | ~idx) key into slot[row];
//                       the LAST arriver (done[b] fetch_add == 15) finalizes.
// Scores are >= +0.0 (fmax(.,0)*positive; x-x==+0 so no -0), so raw f32 bits
// are order-isomorphic and ~idx gives the min-index tie-break => key max
// == (max score, first index), matching jnp.argmax.
__global__ __launch_bounds__(256) void k_score(
    const float* __restrict__ logits, const float* __restrict__ draft,
    const float* __restrict__ invq, const int* __restrict__ topk,
    const int* __restrict__ dids, const int* __restrict__ bonus,
    const float* __restrict__ uniform, const float* __restrict__ ps,
    const float* __restrict__ pm, const int* __restrict__ pidx,
    u64* __restrict__ slot, int* __restrict__ done,
    int B, int S, int V, int chunk_elems, int* __restrict__ out) {
  const int row = blockIdx.y;
  const int chunk = blockIdx.x;
  const int tid = threadIdx.x;
  const int b = row / S;
  const int ownS = row - b * S;
  const bool greedy = (topk[b] == 1);
  const int Sp1 = S + 1;

  __shared__ int sRole;      // 0 exit, 1 scan, 2 greedy-fin, 3 all-acc-fin
  __shared__ float sInvZ;
  __shared__ int sFirst;
  __shared__ float shf[4];
  __shared__ int shi[4];
  __shared__ int sLast;
  __shared__ int tam[8];

  if (tid < 64) {
    if (greedy) {
      if (tid == 0) sRole = (chunk == 0 && ownS == 0) ? 2 : 0;
    } else {
      int a = 1; float Z = 1.f;
      if (tid < S)
        a = accept_row(logits, draft, dids, uniform, ps, b * S + tid, V, Z);
      unsigned long long rej = __ballot(a == 0);
      int first = rej ? (int)__ffsll(rej) - 1 : -1;
      if (tid == ownS) sInvZ = 1.0f / Z;
      if (tid == 0) {
        sFirst = first;
        sRole = (first >= 0) ? (ownS == first ? 1 : 0)
                             : ((chunk == 0 && ownS == 0) ? 3 : 0);
      }
    }
  }
  __syncthreads();
  const int role = sRole;
  if (role == 0) return;

  if (role == 2) {
    // ---- greedy finalize: 64 lanes reduce pm/pidx (s = tid>>4, c = tid&15)
    if (tid < 64) {
      const int s = tid >> 4;
      const int c = tid & 15;
      float m = -INFINITY; int mi = INT_MAX;
      if (s < S) {
        const int oo = (b * S + s) * NCHUNK + c;
        m = pm[oo]; mi = pidx[oo];
      }
      for (int off = 8; off; off >>= 1) {
        float m2 = __shfl_xor(m, off);
        int   i2 = __shfl_xor(mi, off);
        comb_mx(m, mi, m2, i2);
      }
      if (c == 0 && s < S) tam[s] = mi;
    }
    __syncthreads();
    if (tid == 0) {
      int tokv[9];
      bool rejected_before = false, any_rej = false;
      for (int ss = 0; ss < S; ++ss) {
        const int dtok = dids[b * S + ss];
        const int ta = tam[ss];
        const bool rej = (dtok != ta);
        tokv[ss] = rejected_before ? PLACEHOLDER : ta;
        any_rej = any_rej || rej;
        rejected_before = rejected_before || rej;
      }
      tokv[S] = any_rej ? PLACEHOLDER : bonus[b];
      int na = 0;
      for (int j = 0; j < Sp1; ++j) na += (tokv[j] != PLACEHOLDER);
      for (int j = 0; j < Sp1; ++j) out[b * Sp1 + j] = tokv[j];
      out[B * Sp1 + b] = Sp1 - na;
      out[B * Sp1 + B + b] = tokv[na - 1];
    }
    return;
  }

  if (role == 3) {
    // ---- all-accepted finalize: drafts + bonus, 0 rejected
    if (tid == 0) {
      for (int ss = 0; ss < S; ++ss) out[b * Sp1 + ss] = dids[b * S + ss];
      const int bt = bonus[b];
      out[b * Sp1 + S] = bt;
      out[B * Sp1 + b] = 0;
      out[B * Sp1 + B + b] = bt;
    }
    return;
  }

  // ---- role 1: scan this chunk of the first-rejected row ----
  const float invZ = sInvZ;
  const int begin = chunk * chunk_elems;
  const int end = min(begin + chunk_elems, V);
  const int n = max(end - begin, 0);
  const int c4 = n >> 2;
  const float* lrow = logits + (size_t)row * V;
  const float* drow = draft + (size_t)row * V;
  const float* qrow = invq + (size_t)b * V;
  const f32x4* l4 = (const f32x4*)(lrow + begin);
  const f32x4* d4 = (const f32x4*)(drow + begin);
  const f32x4* q4 = (const f32x4*)(qrow + begin);

  float smx = -INFINITY; int si = INT_MAX;
  for (int i = tid; i < c4; i += 256) {
    f32x4 lv = l4[i];                               // L3-resident from pass 1
    f32x4 dv = __builtin_nontemporal_load(d4 + i);  // stream (no reuse)
    f32x4 qv = __builtin_nontemporal_load(q4 + i);  // stream (no reuse)
    const int gi = begin + (i << 2);
#pragma unroll
    for (int k = 0; k < 4; ++k) {
      float p = fexp(lv[k]) * invZ;
      float sc = fmaxf(p - dv[k], 0.f) * qv[k];
      if (sc > smx) { smx = sc; si = gi + k; }
    }
  }
  for (int j = begin + (c4 << 2) + tid; j < end; j += 256) {
    float p = fexp(lrow[j]) * invZ;
    float sc = fmaxf(p - drow[j], 0.f) * qrow[j];
    if (sc > smx) { smx = sc; si = j; }
  }

  const int lane = tid & 63;
  const int wv = tid >> 6;
  for (int off = 32; off; off >>= 1) {
    float m2 = __shfl_xor(smx, off);
    int   i2 = __shfl_xor(si, off);
    comb_mx(smx, si, m2, i2);
  }
  if (lane == 0) { shf[wv] = smx; shi[wv] = si; }
  __syncthreads();
  if (tid == 0) {
#pragma unroll
    for (int w = 1; w < 4; ++w) comb_mx(smx, si, shf[w], shi[w]);
    const u64 key = ((u64)__float_as_uint(smx) << 32) | (unsigned)(~si);
    atomicMax(&slot[row], key);
    __threadfence();
    const int old = __hip_atomic_fetch_add(&done[b], 1, __ATOMIC_ACQ_REL,
                                           __HIP_MEMORY_SCOPE_AGENT);
    sLast = (old == NCHUNK - 1);
  }
  __syncthreads();
  if (sLast && tid == 0) {
    __threadfence();
    const u64 key = __hip_atomic_load(&slot[row], __ATOMIC_ACQUIRE,
                                      __HIP_MEMORY_SCOPE_AGENT);
    const int rec = ~(int)(unsigned)(key & 0xFFFFFFFFull);
    const int first = sFirst;
    for (int ss = 0; ss < S; ++ss)
      out[b * Sp1 + ss] = (ss < first) ? dids[b * S + ss]
                        : (ss == first ? rec : PLACEHOLDER);
    out[b * Sp1 + S] = PLACEHOLDER;          // bonus rejected (any_rej)
    out[B * Sp1 + b] = S - first;            // (S+1) - (first+1)
    out[B * Sp1 + B + b] = rec;              // last accepted = recovered
  }
}

extern "C" void kernel_launch(void* const* d_in, const int* in_sizes, int n_in,
                              void* d_out, int out_size, void* d_ws, size_t ws_size,
                              hipStream_t stream) {
  const float* logits = (const float*)d_in[0];
  const float* draft  = (const float*)d_in[1];
  const int*   dids   = (const int*)d_in[2];
  const int*   bonus  = (const int*)d_in[3];
  const int*   topk   = (const int*)d_in[4];
  const float* unif   = (const float*)d_in[5];
  const float* invq   = (const float*)d_in[6];
  int* out = (int*)d_out;

  const int B = in_sizes[3];
  const int S = in_sizes[2] / B;
  const int V = in_sizes[0] / in_sizes[2];
  const int nrows = B * S;
  const int nitems = nrows * NCHUNK;

  char* w = (char*)d_ws;
  float* pm   = (float*)w; w += (size_t)nitems * sizeof(float);
  float* ps   = (float*)w; w += (size_t)nitems * sizeof(float);
  int*   pidx = (int*)w;   w += (size_t)nitems * sizeof(int);
  u64*   slot = (u64*)w;   w += (size_t)nrows * sizeof(u64);
  int*   done = (int*)w;   w += (size_t)B * sizeof(int);

  int chunk_elems = (V + NCHUNK - 1) / NCHUNK;
  chunk_elems = (chunk_elems + 3) & ~3;   // float4-aligned chunk starts

  dim3 grid1(NCHUNK, nrows);
  k_stats<<<grid1, dim3(256), 0, stream>>>(logits, topk, pm, ps, pidx,
                                           slot, done, S, V, chunk_elems);
  k_score<<<grid1, dim3(256), 0, stream>>>(
      logits, draft, invq, topk, dids, bonus, unif, ps, pm, pidx,
      slot, done, B, S, V, chunk_elems, out);
}

// Round 9
// 43.258 us; speedup vs baseline: 2.0722x; 2.0722x over previous
//
#include <hip/hip_runtime.h>
#include <math.h>
#include <limits.h>

#define NCHUNK 16
#define PLACEHOLDER (-1)

typedef float f32x4 __attribute__((ext_vector_type(4)));

// exp(x - 16), computed as exp2(x*log2e - 16*log2e). No running max needed:
// logits are O(1), so terms are ~1e-7 and the 128K-term sum ~1e-2 -- all
// comfortably inside f32 range. Softmax p = fexp(l) / sum(fexp(l)).
__device__ __forceinline__ float fexp(float x) {
  return exp2f(fmaf(x, 1.44269504088896340736f, -23.0831206542234143f));
}

// (max, index) combine with first-occurrence tie-break (lower index wins).
__device__ __forceinline__ void comb_mx(float& m, int& i, float m2, int i2) {
  if (m2 > m || (m2 == m && i2 < i)) { m = m2; i = i2; }
}

// Accept decision for one row. MUST be bitwise-identical wherever called
// (k_score prologue and k_finalize): linear Z sum in chunk order, fexp,
// divide, compare. Returns 1 = accept. Also outputs Z.
__device__ __forceinline__ int accept_row(
    const float* __restrict__ logits, const float* __restrict__ draft,
    const int* __restrict__ dids, const float* __restrict__ uniform,
    const float* __restrict__ ps, int row, int V, float& Zout) {
  float Z = 0.f;
#pragma unroll
  for (int c = 0; c < NCHUNK; ++c) Z += ps[row * NCHUNK + c];
  Zout = Z;
  const int tok = dids[row];
  const float t_at = fexp(logits[(size_t)row * V + tok]) / Z;
  const float d_at = draft[(size_t)row * V + tok];
  const float u = uniform[row];
  return (d_at > 0.f && (t_at / d_at) >= u) ? 1 : 0;
}

// Pass 1: greedy rows -> per-chunk {max, argmax} (no expf);
//         random rows -> per-chunk sum of exp(l - 16) (branchless).
__global__ __launch_bounds__(256) void k_stats(
    const float* __restrict__ logits, const int* __restrict__ topk,
    float* __restrict__ pm, float* __restrict__ ps, int* __restrict__ pidx,
    int S, int V, int chunk_elems) {
  const int row = blockIdx.y;
  const int chunk = blockIdx.x;
  const int tid = threadIdx.x;
  const int b = row / S;
  const int begin = chunk * chunk_elems;
  const int end = min(begin + chunk_elems, V);
  const int n = max(end - begin, 0);
  const int c4 = n >> 2;
  const float* lrow = logits + (size_t)row * V;
  const f32x4* l4 = (const f32x4*)(lrow + begin);
  const int item = row * NCHUNK + chunk;

  __shared__ float shf[4];
  __shared__ int shi[4];
  const int lane = tid & 63;
  const int wv = tid >> 6;

  if (topk[b] == 1) {
    // ---- greedy: max + argmax only ----
    float m = -INFINITY; int mi = INT_MAX;
    for (int i = tid; i < c4; i += 256) {
      f32x4 v = l4[i];
      const int gi = begin + (i << 2);
#pragma unroll
      for (int k = 0; k < 4; ++k)
        if (v[k] > m) { m = v[k]; mi = gi + k; }   // strict >: first idx kept
    }
    for (int j = begin + (c4 << 2) + tid; j < end; j += 256) {
      float x = lrow[j];
      if (x > m) { m = x; mi = j; }
    }
    for (int off = 32; off; off >>= 1) {
      float m2 = __shfl_xor(m, off);
      int   i2 = __shfl_xor(mi, off);
      comb_mx(m, mi, m2, i2);
    }
    if (lane == 0) { shf[wv] = m; shi[wv] = mi; }
    __syncthreads();
    if (tid == 0) {
#pragma unroll
      for (int w = 1; w < 4; ++w) comb_mx(m, mi, shf[w], shi[w]);
      pm[item] = m; pidx[item] = mi;
    }
  } else {
    // ---- random: branchless sum of exp(l - 16) ----
    float ssum = 0.f;
    for (int i = tid; i < c4; i += 256) {
      f32x4 v = l4[i];
      ssum += fexp(v[0]); ssum += fexp(v[1]);
      ssum += fexp(v[2]); ssum += fexp(v[3]);
    }
    for (int j = begin + (c4 << 2) + tid; j < end; j += 256)
      ssum += fexp(lrow[j]);
    for (int off = 32; off; off >>= 1)
      ssum += __shfl_xor(ssum, off);
    if (lane == 0) shf[wv] = ssum;
    __syncthreads();
    if (tid == 0)
      ps[item] = shf[0] + shf[1] + shf[2] + shf[3];
  }
}

// Pass 2: recovered-token argmax, ONLY for the first-rejected row of each
// non-greedy b. Grid is (NCHUNK, B): one block per (chunk, batch element);
// the block derives the target row itself in a short L2-resident prologue.
// NO inter-block sync of any kind (device-scope atomics/fences measured
// catastrophic on gfx950: R3/R4/R8).
__global__ __launch_bounds__(256) void k_score(
    const float* __restrict__ logits, const float* __restrict__ draft,
    const float* __restrict__ invq, const int* __restrict__ topk,
    const int* __restrict__ dids, const float* __restrict__ uniform,
    const float* __restrict__ ps,
    int S, int V, int chunk_elems,
    float* __restrict__ psm, int* __restrict__ psi) {
  const int b = blockIdx.y;
  if (topk[b] == 1) return;
  const int tid = threadIdx.x;
  const int chunk = blockIdx.x;

  // ---- prologue: find first-rejected row of b (none -> exit) ----
  __shared__ float sInvZ;
  __shared__ int sRow;
  if (tid < 64) {
    int a = 1; float Z = 1.f;
    if (tid < S)
      a = accept_row(logits, draft, dids, uniform, ps, b * S + tid, V, Z);
    unsigned long long rej = __ballot(a == 0);
    int first = rej ? (int)__ffsll(rej) - 1 : -1;
    if (tid == 0) sRow = (first >= 0) ? (b * S + first) : -1;
    // lane `first` holds the Z of the first-rejected row
    float Zf = __shfl(Z, first < 0 ? 0 : first);
    if (tid == 0) sInvZ = 1.0f / Zf;
  }
  __syncthreads();
  const int row = sRow;
  if (row < 0) return;
  const float invZ = sInvZ;
  const int item = row * NCHUNK + chunk;

  const int begin = chunk * chunk_elems;
  const int end = min(begin + chunk_elems, V);
  const int n = max(end - begin, 0);
  const int c4 = n >> 2;
  const float* lrow = logits + (size_t)row * V;
  const float* drow = draft + (size_t)row * V;
  const float* qrow = invq + (size_t)b * V;
  const f32x4* l4 = (const f32x4*)(lrow + begin);
  const f32x4* d4 = (const f32x4*)(drow + begin);
  const f32x4* q4 = (const f32x4*)(qrow + begin);

  __shared__ float shf[4];
  __shared__ int shi[4];
  float smx = -INFINITY; int si = INT_MAX;
  for (int i = tid; i < c4; i += 256) {
    f32x4 lv = l4[i];                               // L3-resident from pass 1
    f32x4 dv = __builtin_nontemporal_load(d4 + i);  // stream (no reuse)
    f32x4 qv = __builtin_nontemporal_load(q4 + i);  // stream (no reuse)
    const int gi = begin + (i << 2);
#pragma unroll
    for (int k = 0; k < 4; ++k) {
      float p = fexp(lv[k]) * invZ;
      float sc = fmaxf(p - dv[k], 0.f) * qv[k];
      if (sc > smx) { smx = sc; si = gi + k; }
    }
  }
  for (int j = begin + (c4 << 2) + tid; j < end; j += 256) {
    float p = fexp(lrow[j]) * invZ;
    float sc = fmaxf(p - drow[j], 0.f) * qrow[j];
    if (sc > smx) { smx = sc; si = j; }
  }

  const int lane = tid & 63;
  const int wv = tid >> 6;
  for (int off = 32; off; off >>= 1) {
    float m2 = __shfl_xor(smx, off);
    int   i2 = __shfl_xor(si, off);
    comb_mx(smx, si, m2, i2);
  }
  if (lane == 0) { shf[wv] = smx; shi[wv] = si; }
  __syncthreads();
  if (tid == 0) {
#pragma unroll
    for (int w = 1; w < 4; ++w) comb_mx(smx, si, shf[w], shi[w]);
    psm[item] = smx; psi[item] = si;
  }
}

// Finalize: one block (64 threads) per batch element b. Recomputes accept
// bits with code identical to k_score's prologue; reads psm/psi ONLY for
// the first-rejected row (the one k_score populated).
__global__ __launch_bounds__(64) void k_finalize(
    const float* __restrict__ logits, const float* __restrict__ draft,
    const int* __restrict__ dids, const int* __restrict__ bonus,
    const int* __restrict__ topk, const float* __restrict__ uniform,
    const float* __restrict__ pm, const int* __restrict__ pidx,
    const float* __restrict__ ps,
    const float* __restrict__ psm, const int* __restrict__ psi,
    int B, int S, int V, int* __restrict__ out) {
  const int b = blockIdx.x;
  const int lane = threadIdx.x;
  const bool greedy = (topk[b] == 1);

  __shared__ int tam[8];
  __shared__ int sFirst;

  if (greedy) {
    if (lane < S) {
      const int row = b * S + lane;
      float m = -INFINITY; int mi = INT_MAX;
#pragma unroll
      for (int c = 0; c < NCHUNK; ++c)
        comb_mx(m, mi, pm[row * NCHUNK + c], pidx[row * NCHUNK + c]);
      tam[lane] = mi;
    }
  } else {
    int a = 1; float Z;
    if (lane < S)
      a = accept_row(logits, draft, dids, uniform, ps, b * S + lane, V, Z);
    unsigned long long rej = __ballot(a == 0);
    if (lane == 0) sFirst = rej ? (int)__ffsll(rej) - 1 : -1;
  }
  __syncthreads();

  if (lane == 0) {
    int tokv[9];
    bool rejected_before = false, any_rej = false;
    int first = greedy ? -1 : sFirst;
    int rectok = 0;
    if (!greedy && first >= 0) {
      const int row = b * S + first;
      float m = -INFINITY; int mi = INT_MAX;
#pragma unroll
      for (int c = 0; c < NCHUNK; ++c)
        comb_mx(m, mi, psm[row * NCHUNK + c], psi[row * NCHUNK + c]);
      rectok = mi;
    }
    for (int ss = 0; ss < S; ++ss) {
      const int r = b * S + ss;
      const int dtok = dids[r];
      int t; bool rej;
      if (greedy) {
        const int ta = tam[ss];
        rej = (dtok != ta);
        t = ta;
      } else {
        rej = (ss == first);
        t = rej ? rectok : dtok;
      }
      tokv[ss] = rejected_before ? PLACEHOLDER : t;
      any_rej = any_rej || rej;
      rejected_before = rejected_before || rej;
    }
    tokv[S] = any_rej ? PLACEHOLDER : bonus[b];
    int na = 0;
    const int Sp1 = S + 1;
    for (int j = 0; j < Sp1; ++j) na += (tokv[j] != PLACEHOLDER);
    for (int j = 0; j < Sp1; ++j) out[b * Sp1 + j] = tokv[j];
    out[B * Sp1 + b] = Sp1 - na;            // num_rejected_tokens
    out[B * Sp1 + B + b] = tokv[na - 1];    // last_token_ids
  }
}

extern "C" void kernel_launch(void* const* d_in, const int* in_sizes, int n_in,
                              void* d_out, int out_size, void* d_ws, size_t ws_size,
                              hipStream_t stream) {
  const float* logits = (const float*)d_in[0];
  const float* draft  = (const float*)d_in[1];
  const int*   dids   = (const int*)d_in[2];
  const int*   bonus  = (const int*)d_in[3];
  const int*   topk   = (const int*)d_in[4];
  const float* unif   = (const float*)d_in[5];
  const float* invq   = (const float*)d_in[6];
  int* out = (int*)d_out;

  const int B = in_sizes[3];
  const int S = in_sizes[2] / B;
  const int V = in_sizes[0] / in_sizes[2];
  const int nrows = B * S;
  const int nitems = nrows * NCHUNK;

  char* w = (char*)d_ws;
  float* pm   = (float*)w; w += (size_t)nitems * sizeof(float);
  float* ps   = (float*)w; w += (size_t)nitems * sizeof(float);
  int*   pidx = (int*)w;   w += (size_t)nitems * sizeof(int);
  float* psm  = (float*)w; w += (size_t)nitems * sizeof(float);
  int*   psi  = (int*)w;   w += (size_t)nitems * sizeof(int);

  int chunk_elems = (V + NCHUNK - 1) / NCHUNK;
  chunk_elems = (chunk_elems + 3) & ~3;   // float4-aligned chunk starts

  dim3 grid1(NCHUNK, nrows);
  dim3 grid2(NCHUNK, B);
  k_stats<<<grid1, dim3(256), 0, stream>>>(logits, topk, pm, ps, pidx,
                                           S, V, chunk_elems);
  k_score<<<grid2, dim3(256), 0, stream>>>(
      logits, draft, invq, topk, dids, unif, ps, S, V, chunk_elems, psm, psi);
  k_finalize<<<dim3(B), dim3(64), 0, stream>>>(
      logits, draft, dids, bonus, topk, unif, pm, pidx, ps, psm, psi,
      B, S, V, out);
}